// Round 10
// baseline (218.466 us; speedup 1.0000x reference)
//
#include <hip/hip_runtime.h>

// AdaIN on MI355X — 5-dispatch pipeline with index binning.
// content: (Nc=1e6, C=64) f32, style: (Ns=2.5e5, C=64) f32, B=16 segments.
// Scatter-accumulate history: LDS atomics ~200cyc (R1,R7); if-converted
// switch 80 VALU/row (R6, 143us); branch tree (R8, ~109us); LDS RMW chain
// (R9, ~107us). All serialize AT the accumulation. R10: bin row-IDS first
// (ballot/popc, ~1 instr/row on 5MB of indices), then reduce each bin with
// ZERO branches and 2 register accumulators — rows are 256B contiguous so
// gather order doesn't hurt coalescing.
// memset -> bin_pass -> binned_reduce -> finalize -> apply.

#define NB 16          // num_batches
#define NC 64          // channels (== wavefront size)
#define NREP 16        // global partial-buffer replicas

#define CSTRIDE 66560  // content per-bin capacity (mean 62500, +16 sigma)
#define SSTRIDE 16896  // style per-bin capacity   (mean 15625, +10 sigma)
#define PA_CHUNK 1024  // rows per wave-chunk in bin_pass

#define CB_BLOCKS 1280 // binned_reduce content blocks: 5120 waves, 320 chunks/bin
#define SB_BLOCKS 320  // style: 1280 waves, 80 chunks/bin
#define CB_CL 208      // 320*208 = 66560 = CSTRIDE
#define SB_CL 212      // 80*212 = 16960 >= SSTRIDE

typedef float fvec4 __attribute__((ext_vector_type(4)));   // nontemporal-ok

// ws float-offset layout:
#define WS_CPART 0                         // NREP*2048 (sum[1024], sumsq[1024])
#define WS_SPART (NREP * 2048)             // NREP*2048
#define WS_SCALE (2 * NREP * 2048)         // 1024
#define WS_BIAS  (WS_SCALE + 1024)         // 1024
#define WS_GCNT  (WS_BIAS + 1024)          // 32 ints: [16 content][16 style]
#define WS_ZERO_FLOATS (WS_GCNT + 32)
#define WS_CBIN  (WS_ZERO_FLOATS + 32)     // int[16 * CSTRIDE]
#define WS_SBIN  (WS_CBIN + 16 * CSTRIDE)  // int[16 * SSTRIDE]

__device__ __forceinline__ int mbcnt64(unsigned long long m)
{
    return __builtin_amdgcn_mbcnt_hi((unsigned)(m >> 32),
           __builtin_amdgcn_mbcnt_lo((unsigned)m, 0));
}

// ---- pass A: bin row ids by batch index --------------------------------------

__global__ __launch_bounds__(256) void bin_pass(
    const int* __restrict__ ci, int Nc, const int* __restrict__ si, int Ns,
    int* __restrict__ gcnt, int* __restrict__ cbin, int* __restrict__ sbin)
{
    const int lane = threadIdx.x & 63;
    const int gw   = blockIdx.x * 4 + (threadIdx.x >> 6);
    const int cchunks = (Nc + PA_CHUNK - 1) / PA_CHUNK;
    const int schunks = (Ns + PA_CHUNK - 1) / PA_CHUNK;

    const int* idx; int n; int* bins; int* cnt; int stride; int chunk;
    if (gw < cchunks)                 { idx = ci; n = Nc; bins = cbin; cnt = gcnt;      stride = CSTRIDE; chunk = gw; }
    else if (gw < cchunks + schunks)  { idx = si; n = Ns; bins = sbin; cnt = gcnt + 16; stride = SSTRIDE; chunk = gw - cchunks; }
    else return;

    const int r0 = chunk * PA_CHUNK;
    const int r1 = (r0 + PA_CHUNK < n) ? (r0 + PA_CHUNK) : n;

    // phase 1: per-bin counts for this chunk (ballot + popc, SALU-heavy)
    int c[NB];
    #pragma unroll
    for (int b = 0; b < NB; ++b) c[b] = 0;
    for (int g = r0; g < r1; g += 64) {
        int v = 255;
        if (g + lane < r1) v = idx[g + lane];
        #pragma unroll
        for (int b = 0; b < NB; ++b)
            c[b] += __popcll(__ballot(v == b));
    }
    // lane b holds its bin's count; one 16-lane atomic gets global bases
    int mycnt = 0;
    #pragma unroll
    for (int b = 0; b < NB; ++b) mycnt = (lane == b) ? c[b] : mycnt;
    int base = 0;
    if (lane < NB) base = atomicAdd(&cnt[lane], mycnt);

    // phase 2: scatter row ids to bins[v][base + rank]
    for (int g = r0; g < r1; g += 64) {
        const int r = g + lane;
        int v = 255;
        if (r < r1) v = idx[r];
        int rank = 0, cadv = 0;
        #pragma unroll
        for (int b = 0; b < NB; ++b) {
            const unsigned long long m = __ballot(v == b);
            rank = (v == b) ? mbcnt64(m) : rank;          // rank among same-bin lanes below
            cadv = (lane == b) ? __popcll(m) : cadv;      // this group's count, in lane b
        }
        const int mybase = __shfl(base, v & 15);          // bin v's running base
        if (r < r1) bins[v * stride + mybase + rank] = r;
        base += cadv;                                     // advance (lanes 0..15)
    }
}

// ---- pass B: reduce each bin, zero branches ----------------------------------

__global__ __launch_bounds__(256) void binned_reduce(
    const float* __restrict__ content, const float* __restrict__ style,
    const int* __restrict__ gcnt, const int* __restrict__ cbin,
    const int* __restrict__ sbin, float* __restrict__ ws)
{
    const int lane = threadIdx.x & 63;
    int gw = blockIdx.x * 4 + (threadIdx.x >> 6);

    const float* feats; const int* bins; const int* cnt; float* part;
    int stride, CL;
    if (blockIdx.x < CB_BLOCKS) {
        feats = content; bins = cbin; cnt = gcnt;      part = ws + WS_CPART;
        stride = CSTRIDE; CL = CB_CL;
    } else {
        gw -= CB_BLOCKS * 4;
        feats = style;   bins = sbin; cnt = gcnt + 16; part = ws + WS_SPART;
        stride = SSTRIDE; CL = SB_CL;
    }

    const int b = gw & 15;
    const int k = gw >> 4;
    const int n = __builtin_amdgcn_readfirstlane(cnt[b]);   // bin size
    const int r0 = k * CL;
    const int r1 = (r0 + CL < n) ? (r0 + CL) : n;

    float s = 0.f, q = 0.f;
    const int* bl = bins + b * stride;

    for (int g = r0; g < r1; g += 64) {
        const int lim = (r1 - g < 64) ? (r1 - g) : 64;
        const int rv = bl[g + ((lane < lim) ? lane : (lim - 1))];  // coalesced ids
        int j = 0;
        for (; j + 8 <= lim; j += 8) {
            float val[8];
            #pragma unroll
            for (int t = 0; t < 8; ++t) {
                const int rid = __builtin_amdgcn_readlane(rv, j + t);
                val[t] = feats[(size_t)rid * NC + lane];    // 256B coalesced row
            }
            #pragma unroll
            for (int t = 0; t < 8; ++t) { s += val[t]; q = fmaf(val[t], val[t], q); }
        }
        for (; j < lim; ++j) {
            const int rid = __builtin_amdgcn_readlane(rv, j);
            const float v = feats[(size_t)rid * NC + lane];
            s += v; q = fmaf(v, v, q);
        }
    }

    float* dst = part + (gw & (NREP - 1)) * 2048;
    atomicAdd(&dst[b * NC + lane], s);
    atomicAdd(&dst[1024 + b * NC + lane], q);
}

// ---- finalize: EMA scan + fused scale/bias -----------------------------------

__global__ void finalize_kernel(float* __restrict__ ws)
{
    if (threadIdx.x >= NC) return;
    const int c = threadIdx.x;
    const float* c_part = ws + WS_CPART;
    const float* s_part = ws + WS_SPART;
    const int*   gcnt   = (const int*)(ws + WS_GCNT);
    float* scale = ws + WS_SCALE;
    float* bias  = ws + WS_BIAS;

    float gm = 0.f, gs = 0.f;
    for (int b = 0; b < NB; ++b) {
        float csum = 0.f, csq = 0.f, ssum = 0.f, ssq = 0.f;
        #pragma unroll
        for (int rep = 0; rep < NREP; ++rep) {
            csum += c_part[rep * 2048 + b * NC + c];
            csq  += c_part[rep * 2048 + 1024 + b * NC + c];
            ssum += s_part[rep * 2048 + b * NC + c];
            ssq  += s_part[rep * 2048 + 1024 + b * NC + c];
        }
        const float ccnt = (float)gcnt[b];
        const float scnt = (float)gcnt[16 + b];
        const float smean = ssum / scnt;
        const float svar  = (ssq - scnt * smean * smean) / (scnt - 1.0f);
        const float sstd  = sqrtf(fmaxf(svar, 0.f)) + 1e-8f;
        if (b == 0) { gm = smean; gs = sstd; }
        else        { gm = 0.9f * gm + 0.1f * smean; gs = 0.9f * gs + 0.1f * sstd; }
        const float cmean = csum / ccnt;
        const float cvar  = (csq - ccnt * cmean * cmean) / (ccnt - 1.0f);
        const float cstd  = sqrtf(fmaxf(cvar, 0.f)) + 1e-8f;
        const float sc = gs / cstd;        // out = sc*x + bi
        scale[b * NC + c] = sc;
        bias [b * NC + c] = gm - sc * cmean;
    }
}

// ---- apply -------------------------------------------------------------------

__global__ __launch_bounds__(256) void apply_kernel(
    const float* __restrict__ content, const int* __restrict__ ci, int Nc,
    const float* __restrict__ ws, fvec4* __restrict__ out4)
{
    __shared__ fvec4 s_sc[NB * 17];        // stride-17 pad
    __shared__ fvec4 s_bi[NB * 17];
    const fvec4* scale4 = (const fvec4*)(ws + WS_SCALE);
    const fvec4* bias4  = (const fvec4*)(ws + WS_BIAS);
    for (int i = threadIdx.x; i < NB * 16; i += 256) {
        const int b = i >> 4, c4 = i & 15;
        s_sc[b * 17 + c4] = scale4[i];
        s_bi[b * 17 + c4] = bias4[i];
    }
    __syncthreads();

    const fvec4* feats4 = (const fvec4*)content;
    const int total4 = Nc * 16;
    const int stride = gridDim.x * 256;
    for (int i = blockIdx.x * 256 + threadIdx.x; i < total4; i += stride) {
        const int r  = i >> 4;
        const int c4 = i & 15;
        const int b  = ci[r];
        const fvec4 v  = feats4[i];
        const fvec4 sc = s_sc[b * 17 + c4];
        const fvec4 bi = s_bi[b * 17 + c4];
        fvec4 o;
        o.x = fmaf(sc.x, v.x, bi.x);
        o.y = fmaf(sc.y, v.y, bi.y);
        o.z = fmaf(sc.z, v.z, bi.z);
        o.w = fmaf(sc.w, v.w, bi.w);
        __builtin_nontemporal_store(o, &out4[i]);
    }
}

// ---- launcher ----------------------------------------------------------------

extern "C" void kernel_launch(void* const* d_in, const int* in_sizes, int n_in,
                              void* d_out, int out_size, void* d_ws, size_t ws_size,
                              hipStream_t stream)
{
    const float* content = (const float*)d_in[0];
    const float* style   = (const float*)d_in[1];
    const int*   ci      = (const int*)d_in[2];
    const int*   si      = (const int*)d_in[3];

    const int Nc = in_sizes[0] / NC;   // 1,000,000
    const int Ns = in_sizes[1] / NC;   //   250,000

    float* ws   = (float*)d_ws;
    int*   gcnt = (int*)(ws + WS_GCNT);
    int*   cbin = (int*)(ws + WS_CBIN);
    int*   sbin = (int*)(ws + WS_SBIN);

    // ws never re-poisoned between replays: zero accumulators + counters.
    (void)hipMemsetAsync(ws, 0, WS_ZERO_FLOATS * sizeof(float), stream);

    const int cchunks = (Nc + PA_CHUNK - 1) / PA_CHUNK;
    const int schunks = (Ns + PA_CHUNK - 1) / PA_CHUNK;
    const int pa_blocks = (cchunks + schunks + 3) / 4;

    bin_pass<<<pa_blocks, 256, 0, stream>>>(ci, Nc, si, Ns, gcnt, cbin, sbin);
    binned_reduce<<<CB_BLOCKS + SB_BLOCKS, 256, 0, stream>>>(
        content, style, gcnt, cbin, sbin, ws);
    finalize_kernel<<<1, 64, 0, stream>>>(ws);
    apply_kernel<<<2048, 256, 0, stream>>>(content, ci, Nc, ws, (fvec4*)d_out);
}

// Round 11
// 184.363 us; speedup vs baseline: 1.1850x; 1.1850x over previous
//
#include <hip/hip_runtime.h>

// AdaIN on MI355X — 4-dispatch pipeline, MFMA-based segment reduction.
// content: (Nc=1e6, C=64) f32, style: (Ns=2.5e5, C=64) f32, B=16 segments.
// Scatter-accumulate history: LDS atomics ~200cyc (R1,R7); if-converted switch
// 80 VALU/row (R6,143us); branch tree (R8,~109us); LDS RMW chain (R9,~107us);
// binning (R10, regressed). R11: segment-sum AS MATMUL — S=E^T·X, Q=E^T·X^2
// with E = one-hot(idx): mfma_f32_16x16x32_bf16, A=one-hot (exact in bf16),
// B=X tile loaded directly in fragment layout. ~5 VALU/row -> memory-bound.
// K-map errors cancel (same map for A and B; sum over k is perm-invariant).
// memset -> mfma reduce -> finalize -> apply.

#define NB 16          // num_batches
#define NC 64          // channels
#define NREP 16        // global partial-buffer replicas
#define CBLKS 1024     // content blocks: 4096 waves, 8 tiles/wave
#define SBLKS 256      // style blocks:   1024 waves, 8 tiles/wave

typedef float fvec4 __attribute__((ext_vector_type(4)));   // nontemporal-ok
typedef float f32x4 __attribute__((ext_vector_type(4)));
typedef short bf16x8 __attribute__((ext_vector_type(8)));

// ws float-offset layout:
#define WS_CPART 0                        // NREP * 2048 (sum[1024], sumsq[1024])
#define WS_SPART (NREP * 2048)            // NREP * 2048
#define WS_CCNT  (2 * NREP * 2048)        // NREP * 16
#define WS_SCNT  (WS_CCNT + NREP * NB)    // NREP * 16
#define WS_SCALE (WS_SCNT + NREP * NB)    // 1024
#define WS_BIAS  (WS_SCALE + 1024)        // 1024
#define WS_ZERO_FLOATS WS_SCALE

__device__ __forceinline__ unsigned cvtpk(float lo, float hi)
{
    unsigned r;
    asm("v_cvt_pk_bf16_f32 %0, %1, %2" : "=v"(r) : "v"(lo), "v"(hi));
    return r;
}

__device__ __forceinline__ void reduce_body(
    const float* __restrict__ feats, const int* __restrict__ idx, int nrows,
    float* __restrict__ part, float* __restrict__ cntp,
    int blk, int nblk, int tid, float* lsum /*4*2048 floats = 32 KB*/)
{
    const int lane = tid & 63;
    const int wv   = tid >> 6;
    const int half = lane >> 4;            // k-group 0..3
    const int sub  = lane & 15;            // A-row (batch) / B-col (channel)

    f32x4 accS[4], accQ[4];
    #pragma unroll
    for (int q = 0; q < 4; ++q) { accS[q] = f32x4{0,0,0,0}; accQ[q] = f32x4{0,0,0,0}; }
    int cnti = 0;

    const int ntiles = (nrows + 31) >> 5;  // 32-row tiles
    const int W   = nblk * 4;
    const int tpw = (ntiles + W - 1) / W;
    const int w   = blk * 4 + wv;
    int t0 = w * tpw;
    int t1 = t0 + tpw; if (t1 > ntiles) t1 = ntiles;

    for (int t = t0; t < t1; ++t) {
        const int rb = t << 5;
        const int rl = rb + (lane & 31);
        const int vidx = (rl < nrows) ? idx[rl] : -1;   // -1 pad: one-hot row = 0

        // ---- counts: 16 ballots, lane b keeps bin b's count ----
        #pragma unroll
        for (int b = 0; b < NB; ++b) {
            const unsigned long long m = __ballot(vidx == b) & 0xFFFFFFFFull;
            cnti += (lane == b) ? (int)__popcll(m) : 0;
        }

        // ---- A fragment: one-hot E^T, elem j -> k = half*8+j, m = sub ----
        union { unsigned w[4]; bf16x8 v; } A;
        const int kb4 = half * 32;         // (half*8)*4 bytes
        #pragma unroll
        for (int i = 0; i < 4; ++i) {
            const int k0 = __builtin_amdgcn_ds_bpermute(kb4 + 8 * i,     vidx);
            const int k1 = __builtin_amdgcn_ds_bpermute(kb4 + 8 * i + 4, vidx);
            const unsigned lo = (k0 == sub) ? 0x3F80u     : 0u;   // bf16(1.0)
            const unsigned hi = (k1 == sub) ? 0x3F800000u : 0u;
            A.w[i] = lo | hi;
        }

        // ---- B values: X[rb + k][q*16 + sub], loaded in fragment layout ----
        float xv[4][8];
        #pragma unroll
        for (int q = 0; q < 4; ++q) {
            #pragma unroll
            for (int j = 0; j < 8; ++j) {
                int r = rb + half * 8 + j;
                if (r > nrows - 1) r = nrows - 1;      // A=0 kills padded rows
                xv[q][j] = feats[(size_t)r * NC + q * 16 + sub];
            }
        }

        // ---- 8 MFMAs: 4 channel-quarters x {sum, sumsq} ----
        #pragma unroll
        for (int q = 0; q < 4; ++q) {
            union { unsigned w[4]; bf16x8 v; } Bs, Bq;
            #pragma unroll
            for (int i = 0; i < 4; ++i) {
                const float a0 = xv[q][2 * i], a1 = xv[q][2 * i + 1];
                Bs.w[i] = cvtpk(a0, a1);
                Bq.w[i] = cvtpk(a0 * a0, a1 * a1);
            }
            accS[q] = __builtin_amdgcn_mfma_f32_16x16x32_bf16(A.v, Bs.v, accS[q], 0, 0, 0);
            accQ[q] = __builtin_amdgcn_mfma_f32_16x16x32_bf16(A.v, Bq.v, accQ[q], 0, 0, 0);
        }
    }

    // ---- merge 4 waves via LDS, flush to this block's replica ----
    // D layout (verified m89/m91): col = lane&15, row = (lane>>4)*4 + reg.
    float* my = lsum + wv * 2048;
    #pragma unroll
    for (int q = 0; q < 4; ++q) {
        #pragma unroll
        for (int i = 0; i < 4; ++i) {
            const int m = half * 4 + i;                // batch
            my[m * NC + q * 16 + sub]        = accS[q][i];
            my[1024 + m * NC + q * 16 + sub] = accQ[q][i];
        }
    }
    __syncthreads();
    float* dst = part + (blk & (NREP - 1)) * 2048;
    for (int i = tid; i < 2048; i += 256)
        atomicAdd(&dst[i], lsum[i] + lsum[2048 + i] + lsum[4096 + i] + lsum[6144 + i]);
    if (lane < NB)
        atomicAdd(&cntp[(blk & (NREP - 1)) * NB + lane], (float)cnti);
}

__global__ __launch_bounds__(256) void reduce_stats(
    const float* __restrict__ content, const int* __restrict__ ci, int Nc,
    const float* __restrict__ style,   const int* __restrict__ si, int Ns,
    float* __restrict__ ws)
{
    __shared__ float lsum[4 * 2048];       // 32 KB -> 5 blocks/CU
    if (blockIdx.x < CBLKS)
        reduce_body(content, ci, Nc, ws + WS_CPART, ws + WS_CCNT,
                    blockIdx.x, CBLKS, threadIdx.x, lsum);
    else
        reduce_body(style, si, Ns, ws + WS_SPART, ws + WS_SCNT,
                    blockIdx.x - CBLKS, SBLKS, threadIdx.x, lsum);
}

__global__ void finalize_kernel(float* __restrict__ ws)
{
    if (threadIdx.x >= NC) return;
    const int c = threadIdx.x;
    const float* c_part = ws + WS_CPART;
    const float* s_part = ws + WS_SPART;
    const float* c_cntp = ws + WS_CCNT;
    const float* s_cntp = ws + WS_SCNT;
    float* scale = ws + WS_SCALE;
    float* bias  = ws + WS_BIAS;

    float gm = 0.f, gs = 0.f;
    for (int b = 0; b < NB; ++b) {
        float csum = 0.f, csq = 0.f, ssum = 0.f, ssq = 0.f, ccnt = 0.f, scnt = 0.f;
        #pragma unroll
        for (int rep = 0; rep < NREP; ++rep) {
            csum += c_part[rep * 2048 + b * NC + c];
            csq  += c_part[rep * 2048 + 1024 + b * NC + c];
            ssum += s_part[rep * 2048 + b * NC + c];
            ssq  += s_part[rep * 2048 + 1024 + b * NC + c];
            ccnt += c_cntp[rep * NB + b];
            scnt += s_cntp[rep * NB + b];
        }
        const float smean = ssum / scnt;
        const float svar  = (ssq - scnt * smean * smean) / (scnt - 1.0f);
        const float sstd  = sqrtf(fmaxf(svar, 0.f)) + 1e-8f;
        if (b == 0) { gm = smean; gs = sstd; }
        else        { gm = 0.9f * gm + 0.1f * smean; gs = 0.9f * gs + 0.1f * sstd; }
        const float cmean = csum / ccnt;
        const float cvar  = (csq - ccnt * cmean * cmean) / (ccnt - 1.0f);
        const float cstd  = sqrtf(fmaxf(cvar, 0.f)) + 1e-8f;
        const float sc = gs / cstd;        // out = sc*x + bi
        scale[b * NC + c] = sc;
        bias [b * NC + c] = gm - sc * cmean;
    }
}

__global__ __launch_bounds__(256) void apply_kernel(
    const float* __restrict__ content, const int* __restrict__ ci, int Nc,
    const float* __restrict__ ws, fvec4* __restrict__ out4)
{
    __shared__ fvec4 s_sc[NB * 17];        // stride-17 pad
    __shared__ fvec4 s_bi[NB * 17];
    const fvec4* scale4 = (const fvec4*)(ws + WS_SCALE);
    const fvec4* bias4  = (const fvec4*)(ws + WS_BIAS);
    for (int i = threadIdx.x; i < NB * 16; i += 256) {
        const int b = i >> 4, c4 = i & 15;
        s_sc[b * 17 + c4] = scale4[i];
        s_bi[b * 17 + c4] = bias4[i];
    }
    __syncthreads();

    const fvec4* feats4 = (const fvec4*)content;
    const int total4 = Nc * 16;
    const int stride = gridDim.x * 256;
    for (int i = blockIdx.x * 256 + threadIdx.x; i < total4; i += stride) {
        const int r  = i >> 4;
        const int c4 = i & 15;
        const int b  = ci[r];
        const fvec4 v  = feats4[i];
        const fvec4 sc = s_sc[b * 17 + c4];
        const fvec4 bi = s_bi[b * 17 + c4];
        fvec4 o;
        o.x = fmaf(sc.x, v.x, bi.x);
        o.y = fmaf(sc.y, v.y, bi.y);
        o.z = fmaf(sc.z, v.z, bi.z);
        o.w = fmaf(sc.w, v.w, bi.w);
        __builtin_nontemporal_store(o, &out4[i]);
    }
}

extern "C" void kernel_launch(void* const* d_in, const int* in_sizes, int n_in,
                              void* d_out, int out_size, void* d_ws, size_t ws_size,
                              hipStream_t stream)
{
    const float* content = (const float*)d_in[0];
    const float* style   = (const float*)d_in[1];
    const int*   ci      = (const int*)d_in[2];
    const int*   si      = (const int*)d_in[3];

    const int Nc = in_sizes[0] / NC;   // 1,000,000
    const int Ns = in_sizes[1] / NC;   //   250,000

    float* ws = (float*)d_ws;
    // ws never re-poisoned between replays: zero accumulators every call.
    (void)hipMemsetAsync(ws, 0, WS_ZERO_FLOATS * sizeof(float), stream);

    reduce_stats<<<CBLKS + SBLKS, 256, 0, stream>>>(content, ci, Nc, style, si, Ns, ws);
    finalize_kernel<<<1, 64, 0, stream>>>(ws);
    apply_kernel<<<2048, 256, 0, stream>>>(content, ci, Nc, ws, (fvec4*)d_out);
}